// Round 5
// baseline (156.923 us; speedup 1.0000x reference)
//
#include <hip/hip_runtime.h>
#include <hip/hip_bf16.h>
#include <cstdint>

#define B_SIZE 4096
#define TWO_B  8192
#define DIM    512
#define NPAIRS 2080          // 64*65/2 upper-triangular tile pairs
// exp(x/t) = exp2(x * log2(e)/t), t = 0.5
#define EXP_SCALE 2.8853900817779268f

typedef __attribute__((ext_vector_type(8))) short short8;   // 8 bf16 = 4 VGPRs
typedef __attribute__((ext_vector_type(4))) float f32x4;

// raw waitcnt: vmcnt(n) with lgkmcnt/expcnt unconstrained (gfx9 encoding)
#define WAITVM(n) __builtin_amdgcn_s_waitcnt(0xF70 | (n))
#define BARRIER() __builtin_amdgcn_s_barrier()

// ---------- helpers ----------
__device__ __forceinline__ unsigned short f2bf(float f) {
    union { float f; unsigned u; } v; v.f = f;
    unsigned r = v.u + 0x7fffu + ((v.u >> 16) & 1u);   // RNE
    return (unsigned short)(r >> 16);
}

__device__ __forceinline__ void async16(const unsigned short* g, unsigned short* l) {
    __builtin_amdgcn_global_load_lds(
        (const __attribute__((address_space(1))) unsigned int*)g,
        (__attribute__((address_space(3))) unsigned int*)l,
        16, 0, 0);
}

// ---------- kernel 1: L2-normalize rows -> bf16 reps, fp32 positives, zero denom ----------
__global__ __launch_bounds__(256) void norm_pos_kernel(
    const float* __restrict__ emb_i, const float* __restrict__ emb_j,
    unsigned short* __restrict__ reps, float* __restrict__ pos,
    float* __restrict__ denom)
{
    __shared__ float sc[3][4];
    int b = blockIdx.x, t = threadIdx.x;
    if (b < 32) denom[b * 256 + t] = 0.0f;     // zero-init, visible at kernel boundary

    const float2* ri = (const float2*)(emb_i + (size_t)b * DIM);
    const float2* rj = (const float2*)(emb_j + (size_t)b * DIM);
    float2 xi = ri[t], xj = rj[t];
    float si = xi.x * xi.x + xi.y * xi.y;
    float sj = xj.x * xj.x + xj.y * xj.y;
    #pragma unroll
    for (int o = 32; o > 0; o >>= 1) { si += __shfl_down(si, o, 64); sj += __shfl_down(sj, o, 64); }
    int lane = t & 63, w = t >> 6;
    if (lane == 0) { sc[0][w] = si; sc[1][w] = sj; }
    __syncthreads();
    float ni2 = sc[0][0] + sc[0][1] + sc[0][2] + sc[0][3];
    float nj2 = sc[1][0] + sc[1][1] + sc[1][2] + sc[1][3];
    float rni = 1.0f / fmaxf(sqrtf(ni2), 1e-12f);
    float rnj = 1.0f / fmaxf(sqrtf(nj2), 1e-12f);
    float zix = xi.x * rni, ziy = xi.y * rni;
    float zjx = xj.x * rnj, zjy = xj.y * rnj;
    unsigned int pi = (unsigned)f2bf(zix) | ((unsigned)f2bf(ziy) << 16);
    unsigned int pj = (unsigned)f2bf(zjx) | ((unsigned)f2bf(zjy) << 16);
    ((unsigned int*)(reps + (size_t)b * DIM))[t]            = pi;
    ((unsigned int*)(reps + (size_t)(b + B_SIZE) * DIM))[t] = pj;
    float d = zix * zjx + ziy * zjy;
    #pragma unroll
    for (int o = 32; o > 0; o >>= 1) d += __shfl_down(d, o, 64);
    if (lane == 0) sc[2][w] = d;
    __syncthreads();
    if (t == 0) pos[b] = sc[2][0] + sc[2][1] + sc[2][2] + sc[2][3];
}

// ---------- kernel 2: symmetric fused R*R^T + masked exp row/col sums ----------
// Restructured K-loop: static double buffer, fine-grained vmcnt(8), raw barriers,
// loads(k+2) issued after the post-compute barrier -> never drains vmcnt(0) mid-loop.
#define BM 128
#define BN 128
#define BK 64
#define KITERS 8             // DIM / BK

__global__ __launch_bounds__(256) void sim_denom_kernel(
    const unsigned short* __restrict__ reps,
    const int* __restrict__ target,
    float* __restrict__ denom)
{
    // swizzled row-major [128][64] bf16 tiles: row r chunk c (16B) stored at pos c^(r&7)
    // 4 distinct static arrays (alias analysis stays precise) = exactly 64 KB
    __shared__ __align__(16) unsigned short As0[BM * BK];
    __shared__ __align__(16) unsigned short As1[BM * BK];
    __shared__ __align__(16) unsigned short Bs0[BM * BK];
    __shared__ __align__(16) unsigned short Bs1[BM * BK];

    int t = threadIdx.x;
    int id = blockIdx.x;

    // --- supertile swizzle: 4x4 supertiles of 16x16 tiles over the 64-tile triangle ---
    const int sI[10]  = {0,0,0,0,1,1,1,2,2,3};
    const int sJ[10]  = {0,1,2,3,1,2,3,2,3,3};
    const int off[11] = {0,136,392,648,904,1040,1296,1552,1688,1944,2080};
    int s = 0;
    while (off[s + 1] <= id) s++;
    int l = id - off[s];
    int u, v;
    if (sI[s] == sJ[s]) {                       // triangular 16x16: start(u)=u*(33-u)/2
        u = 0;
        while (((u + 1) * (32 - u)) / 2 <= l) u++;
        v = u + (l - (u * (33 - u)) / 2);
    } else { u = l >> 4; v = l & 15; }
    int bi = sI[s] * 16 + u;
    int bj = sJ[s] * 16 + v;
    int brow = bi * BM;
    int bcol = bj * BN;

    int wave = t >> 6, lane = t & 63;
    int wr = wave >> 1, wc = wave & 1;       // 2x2 waves, each 64x64 output
    int quad = lane >> 4, lm = lane & 15;

    f32x4 acc[4][4];
    #pragma unroll
    for (int i = 0; i < 4; i++)
        #pragma unroll
        for (int j = 0; j < 4; j++) acc[i][j] = (f32x4)0.0f;

    // staging: per call c (0..3): thread t -> row c*32 + (t>>3), LDS byte c*4096 + t*16,
    // swizzled source chunk cd = (t&7) ^ (row&7)
    int srow = t >> 3;
    int cd   = (t & 7) ^ (srow & 7);
    const unsigned short* gA = reps + (size_t)(brow + srow) * DIM + cd * 8;
    const unsigned short* gB = reps + (size_t)(bcol + srow) * DIM + cd * 8;

    auto stage = [&](unsigned short* Ab, unsigned short* Bb, int k0) {
        #pragma unroll
        for (int c = 0; c < 4; c++) {
            async16(gA + k0 + c * 32 * DIM, Ab + t * 8 + c * 2048);
            async16(gB + k0 + c * 32 * DIM, Bb + t * 8 + c * 2048);
        }
    };
    auto compute = [&](const unsigned short* Ab, const unsigned short* Bb) {
        #pragma unroll
        for (int ss = 0; ss < 2; ss++) {
            short8 af[4], bf[4];
            #pragma unroll
            for (int mi = 0; mi < 4; mi++) {
                int rl = wr * 64 + mi * 16 + lm;
                int p = (ss * 4 + quad) ^ (rl & 7);
                af[mi] = *(const short8*)(Ab + rl * 64 + p * 8);
            }
            #pragma unroll
            for (int ni = 0; ni < 4; ni++) {
                int cl = wc * 64 + ni * 16 + lm;
                int p = (ss * 4 + quad) ^ (cl & 7);
                bf[ni] = *(const short8*)(Bb + cl * 64 + p * 8);
            }
            #pragma unroll
            for (int mi = 0; mi < 4; mi++)
                #pragma unroll
                for (int ni = 0; ni < 4; ni++)
                    acc[mi][ni] = __builtin_amdgcn_mfma_f32_16x16x32_bf16(
                        af[mi], bf[ni], acc[mi][ni], 0, 0, 0);
        }
    };

    // prologue: two tiles in flight
    stage(As0, Bs0, 0);
    stage(As1, Bs1, BK);

    #pragma unroll
    for (int k = 0; k < KITERS; k++) {
        unsigned short* Ac = (k & 1) ? As1 : As0;
        unsigned short* Bc = (k & 1) ? Bs1 : Bs0;
        // wait for loads(k): only loads(k+1)'s 8 DMAs may remain outstanding
        if (k < KITERS - 1) WAITVM(8); else WAITVM(0);
        BARRIER();                         // all waves' loads(k) landed
        compute(Ac, Bc);
        BARRIER();                         // all waves done reading buf(k)
        if (k + 2 < KITERS) stage(Ac, Bc, (k + 2) * BK);
    }

    // epilogue: C/D layout col=lane&15, row=quad*4+reg; labels read direct (L2-hot)
    bool haspos = (bj - bi == 32);   // |rg-cg|==4096 only possible then (at rl==cl)
    int labc[4];
    #pragma unroll
    for (int ni = 0; ni < 4; ni++)
        labc[ni] = target[(bcol + wc * 64 + ni * 16 + lm) & (B_SIZE - 1)];

    float colacc[4] = {0.f, 0.f, 0.f, 0.f};
    #pragma unroll
    for (int mi = 0; mi < 4; mi++) {
        #pragma unroll
        for (int r = 0; r < 4; r++) {
            int rl = wr * 64 + mi * 16 + quad * 4 + r;
            int labr = target[(brow + rl) & (B_SIZE - 1)];
            float rowacc = 0.0f;
            #pragma unroll
            for (int ni = 0; ni < 4; ni++) {
                int cl = wc * 64 + ni * 16 + lm;
                bool pospair = haspos && (rl == cl);
                bool masked = (labr == labc[ni]) && !pospair;
                float e = masked ? 0.0f
                                 : __builtin_amdgcn_exp2f(acc[mi][ni][r] * EXP_SCALE);
                rowacc += e;
                colacc[ni] += e;
            }
            rowacc += __shfl_xor(rowacc, 1, 64);
            rowacc += __shfl_xor(rowacc, 2, 64);
            rowacc += __shfl_xor(rowacc, 4, 64);
            rowacc += __shfl_xor(rowacc, 8, 64);
            if (lm == 0) atomicAdd(&denom[brow + rl], rowacc);
        }
    }
    if (bi != bj) {
        #pragma unroll
        for (int ni = 0; ni < 4; ni++) {
            float c = colacc[ni];
            c += __shfl_xor(c, 16, 64);
            c += __shfl_xor(c, 32, 64);
            if (lane < 16) atomicAdd(&denom[bcol + wc * 64 + ni * 16 + lm], c);
        }
    }
}

// ---------- kernel 3: final loss ----------
__global__ __launch_bounds__(256) void loss_kernel(
    const float* __restrict__ denom, const float* __restrict__ pos,
    float* __restrict__ out)
{
    __shared__ float sc[4];
    int t = threadIdx.x;
    float v = 0.0f;
    for (int i = t; i < TWO_B; i += 256) v += logf(denom[i] + 1e-7f);
    float p = 0.0f;
    for (int i = t; i < B_SIZE; i += 256) p += pos[i];
    // loss = (sum log(denom) - (2/t) * sum pos) / 2B ; 2/t = 4
    float v2 = v - 4.0f * p;
    #pragma unroll
    for (int o = 32; o > 0; o >>= 1) v2 += __shfl_down(v2, o, 64);
    int lane = t & 63, w = t >> 6;
    if (lane == 0) sc[w] = v2;
    __syncthreads();
    if (t == 0) out[0] = (sc[0] + sc[1] + sc[2] + sc[3]) / (float)TWO_B;
}

// ---------- launcher ----------
extern "C" void kernel_launch(void* const* d_in, const int* in_sizes, int n_in,
                              void* d_out, int out_size, void* d_ws, size_t ws_size,
                              hipStream_t stream)
{
    const float* emb_i  = (const float*)d_in[0];
    const float* emb_j  = (const float*)d_in[1];
    const int*   target = (const int*)d_in[2];
    float* out = (float*)d_out;

    char* ws = (char*)d_ws;
    unsigned short* reps = (unsigned short*)ws;                          // 8 MB
    float* pos   = (float*)(ws + (size_t)TWO_B * DIM * 2);               // 16 KB
    float* denom = (float*)(ws + (size_t)TWO_B * DIM * 2 + B_SIZE * 4);  // 32 KB

    norm_pos_kernel<<<B_SIZE, 256, 0, stream>>>(emb_i, emb_j, reps, pos, denom);
    sim_denom_kernel<<<NPAIRS, 256, 0, stream>>>(reps, target, denom);
    loss_kernel<<<1, 256, 0, stream>>>(denom, pos, out);
}

// Round 6
// 123.005 us; speedup vs baseline: 1.2757x; 1.2757x over previous
//
#include <hip/hip_runtime.h>
#include <hip/hip_bf16.h>
#include <cstdint>

#define B_SIZE 4096
#define TWO_B  8192
#define DIM    512           // row length; fp8 => 512 bytes per row
#define NPAIRS 2080          // 64*65/2 upper-triangular tile pairs
// exp(x/t) = exp2(x * log2(e)/t), t = 0.5
#define EXP_SCALE 2.8853900817779268f

typedef __attribute__((ext_vector_type(4))) float f32x4;

// raw waitcnt: vmcnt(n) with lgkmcnt/expcnt unconstrained (gfx9 encoding)
#define WAITVM(n) __builtin_amdgcn_s_waitcnt(0xF70 | (n))
#define BARRIER() __builtin_amdgcn_s_barrier()

// ---------- helpers ----------
__device__ __forceinline__ void async16(const void* g, void* l) {
    __builtin_amdgcn_global_load_lds(
        (const __attribute__((address_space(1))) unsigned int*)g,
        (__attribute__((address_space(3))) unsigned int*)l,
        16, 0, 0);
}

// ---------- kernel 1: L2-normalize rows -> fp8 reps, fp32 positives, zero denom/out ----------
__global__ __launch_bounds__(256) void norm_pos_kernel(
    const float* __restrict__ emb_i, const float* __restrict__ emb_j,
    unsigned char* __restrict__ reps, float* __restrict__ pos,
    float* __restrict__ denom, float* __restrict__ out)
{
    __shared__ float sc[3][4];
    int b = blockIdx.x, t = threadIdx.x;
    if (b < 32) denom[b * 256 + t] = 0.0f;     // zero-init, visible at kernel boundary
    if (b == 32 && t == 0) out[0] = 0.0f;      // loss kernel accumulates atomically

    const float2* ri = (const float2*)(emb_i + (size_t)b * DIM);
    const float2* rj = (const float2*)(emb_j + (size_t)b * DIM);
    float2 xi = ri[t], xj = rj[t];
    float si = xi.x * xi.x + xi.y * xi.y;
    float sj = xj.x * xj.x + xj.y * xj.y;
    #pragma unroll
    for (int o = 32; o > 0; o >>= 1) { si += __shfl_down(si, o, 64); sj += __shfl_down(sj, o, 64); }
    int lane = t & 63, w = t >> 6;
    if (lane == 0) { sc[0][w] = si; sc[1][w] = sj; }
    __syncthreads();
    float ni2 = sc[0][0] + sc[0][1] + sc[0][2] + sc[0][3];
    float nj2 = sc[1][0] + sc[1][1] + sc[1][2] + sc[1][3];
    float rni = 1.0f / fmaxf(sqrtf(ni2), 1e-12f);
    float rnj = 1.0f / fmaxf(sqrtf(nj2), 1e-12f);
    float zix = xi.x * rni, ziy = xi.y * rni;
    float zjx = xj.x * rnj, zjy = xj.y * rnj;
    // pack 2 floats -> 2 OCP e4m3 bytes (HW cvt, gfx950)
    int pki = __builtin_amdgcn_cvt_pk_fp8_f32(zix, ziy, 0, false);
    int pkj = __builtin_amdgcn_cvt_pk_fp8_f32(zjx, zjy, 0, false);
    ((unsigned short*)(reps + (size_t)b * DIM))[t]            = (unsigned short)pki;
    ((unsigned short*)(reps + (size_t)(b + B_SIZE) * DIM))[t] = (unsigned short)pkj;
    float d = zix * zjx + ziy * zjy;
    #pragma unroll
    for (int o = 32; o > 0; o >>= 1) d += __shfl_down(d, o, 64);
    if (lane == 0) sc[2][w] = d;
    __syncthreads();
    if (t == 0) pos[b] = sc[2][0] + sc[2][1] + sc[2][2] + sc[2][3];
}

// ---------- kernel 2: symmetric fused R*R^T (fp8 MFMA) + masked exp row/col sums ----------
// fp8 tiles: 128 rows x 64 B; row r = 4 pieces of 16 B, piece p stored at p ^ ((r^(r>>2))&3)
// => fragment reads are 2-way bank aliased only (free). Double-buffered (32 KB LDS total),
// fine-grained vmcnt(4) + raw barriers: next tile's DMA stays in flight across compute.
#define BM 128
#define BK 64
#define KITERS 8             // DIM / BK

__global__ __launch_bounds__(256) void sim_denom_kernel(
    const unsigned char* __restrict__ reps,
    const int* __restrict__ target,
    float* __restrict__ denom)
{
    __shared__ __align__(16) unsigned char As0[BM * BK];
    __shared__ __align__(16) unsigned char As1[BM * BK];
    __shared__ __align__(16) unsigned char Bs0[BM * BK];
    __shared__ __align__(16) unsigned char Bs1[BM * BK];

    int t = threadIdx.x;
    int id = blockIdx.x;

    // --- supertile swizzle: 4x4 supertiles of 16x16 tiles over the 64-tile triangle ---
    const int sI[10]  = {0,0,0,0,1,1,1,2,2,3};
    const int sJ[10]  = {0,1,2,3,1,2,3,2,3,3};
    const int off[11] = {0,136,392,648,904,1040,1296,1552,1688,1944,2080};
    int s = 0;
    while (off[s + 1] <= id) s++;
    int l = id - off[s];
    int u, v;
    if (sI[s] == sJ[s]) {                       // triangular 16x16: start(u)=u*(33-u)/2
        u = 0;
        while (((u + 1) * (32 - u)) / 2 <= l) u++;
        v = u + (l - (u * (33 - u)) / 2);
    } else { u = l >> 4; v = l & 15; }
    int bi = sI[s] * 16 + u;
    int bj = sJ[s] * 16 + v;
    int brow = bi * BM;
    int bcol = bj * BM;

    int wave = t >> 6, lane = t & 63;
    int wr = wave >> 1, wc = wave & 1;       // 2x2 waves, each 64x64 output
    int quad = lane >> 4, lm = lane & 15;

    f32x4 acc[4][4];
    #pragma unroll
    for (int i = 0; i < 4; i++)
        #pragma unroll
        for (int j = 0; j < 4; j++) acc[i][j] = (f32x4)0.0f;

    // staging: per call c (0..1): thread t -> row c*64 + (t>>2), LDS byte c*4096 + t*16,
    // swizzled source piece = (t&3) ^ ((row ^ (row>>2)) & 3)  [row&3, (row>>2)&3 same for both calls]
    int srow = t >> 2;
    int sp   = (t & 3) ^ ((srow ^ (srow >> 2)) & 3);
    const unsigned char* gA = reps + (size_t)(brow + srow) * DIM + sp * 16;
    const unsigned char* gB = reps + (size_t)(bcol + srow) * DIM + sp * 16;

    auto stage = [&](unsigned char* Ab, unsigned char* Bb, int k0) {
        #pragma unroll
        for (int c = 0; c < 2; c++) {
            async16(gA + k0 + c * 64 * DIM, Ab + t * 16 + c * 4096);
            async16(gB + k0 + c * 64 * DIM, Bb + t * 16 + c * 4096);
        }
    };
    auto compute = [&](const unsigned char* Ab, const unsigned char* Bb) {
        #pragma unroll
        for (int ss = 0; ss < 2; ss++) {       // two K=32 sub-steps of BK=64
            long af[4], bf[4];
            #pragma unroll
            for (int mi = 0; mi < 4; mi++) {
                int rl = wr * 64 + mi * 16 + lm;
                int p = (ss * 2 + (quad >> 1)) ^ ((rl ^ (rl >> 2)) & 3);
                af[mi] = *(const long*)(Ab + rl * 64 + p * 16 + (quad & 1) * 8);
            }
            #pragma unroll
            for (int ni = 0; ni < 4; ni++) {
                int cl = wc * 64 + ni * 16 + lm;
                int p = (ss * 2 + (quad >> 1)) ^ ((cl ^ (cl >> 2)) & 3);
                bf[ni] = *(const long*)(Bb + cl * 64 + p * 16 + (quad & 1) * 8);
            }
            #pragma unroll
            for (int mi = 0; mi < 4; mi++)
                #pragma unroll
                for (int ni = 0; ni < 4; ni++)
                    acc[mi][ni] = __builtin_amdgcn_mfma_f32_16x16x32_fp8_fp8(
                        af[mi], bf[ni], acc[mi][ni], 0, 0, 0);
        }
    };

    // prologue: two tiles in flight (8 DMAs outstanding per wave)
    stage(As0, Bs0, 0);
    stage(As1, Bs1, BK);

    #pragma unroll
    for (int k = 0; k < KITERS; k++) {
        unsigned char* Ac = (k & 1) ? As1 : As0;
        unsigned char* Bc = (k & 1) ? Bs1 : Bs0;
        if (k < KITERS - 1) WAITVM(4); else WAITVM(0);   // drain loads(k), keep loads(k+1) in flight
        BARRIER();                         // all waves' loads(k) landed
        compute(Ac, Bc);
        BARRIER();                         // all waves done reading buf(k)
        if (k + 2 < KITERS) stage(Ac, Bc, (k + 2) * BK);
    }

    // epilogue: C/D layout col=lane&15, row=quad*4+reg; labels read direct (L2-hot)
    bool haspos = (bj - bi == 32);   // |rg-cg|==4096 only possible then (at rl==cl)
    int labc[4];
    #pragma unroll
    for (int ni = 0; ni < 4; ni++)
        labc[ni] = target[(bcol + wc * 64 + ni * 16 + lm) & (B_SIZE - 1)];

    float colacc[4] = {0.f, 0.f, 0.f, 0.f};
    #pragma unroll
    for (int mi = 0; mi < 4; mi++) {
        #pragma unroll
        for (int r = 0; r < 4; r++) {
            int rl = wr * 64 + mi * 16 + quad * 4 + r;
            int labr = target[(brow + rl) & (B_SIZE - 1)];
            float rowacc = 0.0f;
            #pragma unroll
            for (int ni = 0; ni < 4; ni++) {
                int cl = wc * 64 + ni * 16 + lm;
                bool pospair = haspos && (rl == cl);
                bool masked = (labr == labc[ni]) && !pospair;
                float e = masked ? 0.0f
                                 : __builtin_amdgcn_exp2f(acc[mi][ni][r] * EXP_SCALE);
                rowacc += e;
                colacc[ni] += e;
            }
            rowacc += __shfl_xor(rowacc, 1, 64);
            rowacc += __shfl_xor(rowacc, 2, 64);
            rowacc += __shfl_xor(rowacc, 4, 64);
            rowacc += __shfl_xor(rowacc, 8, 64);
            if (lm == 0) atomicAdd(&denom[brow + rl], rowacc);
        }
    }
    if (bi != bj) {
        #pragma unroll
        for (int ni = 0; ni < 4; ni++) {
            float c = colacc[ni];
            c += __shfl_xor(c, 16, 64);
            c += __shfl_xor(c, 32, 64);
            if (lane < 16) atomicAdd(&denom[bcol + wc * 64 + ni * 16 + lm], c);
        }
    }
}

// ---------- kernel 3: final loss (parallel, atomic accumulate into pre-zeroed out) ----------
__global__ __launch_bounds__(256) void loss_kernel(
    const float* __restrict__ denom, const float* __restrict__ pos,
    float* __restrict__ out)
{
    __shared__ float sc[4];
    int t = threadIdx.x, b = blockIdx.x;
    int i = b * 256 + t;
    float v = logf(denom[i] + 1e-7f);                  // 32 blocks x 256 = 8192
    float p = (i < B_SIZE) ? pos[i] : 0.0f;
    // loss = (sum log(denom) - (2/t) * sum pos) / 2B ; 2/t = 4
    float v2 = v - 4.0f * p;
    #pragma unroll
    for (int o = 32; o > 0; o >>= 1) v2 += __shfl_down(v2, o, 64);
    int lane = t & 63, w = t >> 6;
    if (lane == 0) sc[w] = v2;
    __syncthreads();
    if (t == 0) atomicAdd(out, (sc[0] + sc[1] + sc[2] + sc[3]) * (1.0f / (float)TWO_B));
}

// ---------- launcher ----------
extern "C" void kernel_launch(void* const* d_in, const int* in_sizes, int n_in,
                              void* d_out, int out_size, void* d_ws, size_t ws_size,
                              hipStream_t stream)
{
    const float* emb_i  = (const float*)d_in[0];
    const float* emb_j  = (const float*)d_in[1];
    const int*   target = (const int*)d_in[2];
    float* out = (float*)d_out;

    char* ws = (char*)d_ws;
    unsigned char* reps = (unsigned char*)ws;                        // 8192*512 = 4 MB (fp8)
    float* pos   = (float*)(ws + (size_t)TWO_B * DIM);               // 16 KB
    float* denom = (float*)(ws + (size_t)TWO_B * DIM + B_SIZE * 4);  // 32 KB

    norm_pos_kernel<<<B_SIZE, 256, 0, stream>>>(emb_i, emb_j, reps, pos, denom, out);
    sim_denom_kernel<<<NPAIRS, 256, 0, stream>>>(reps, target, denom);
    loss_kernel<<<TWO_B / 256, 256, 0, stream>>>(denom, pos, out);
}